// Round 1
// baseline (943.109 us; speedup 1.0000x reference)
//
#include <hip/hip_runtime.h>
#include <math.h>

#define NEURONS 54
#define DT 4
#define STEPS 30
#define BATCH 16
#define HW 75
#define P 5625        // 75*75
#define PPAD 5632     // padded to multiple of 4 (16B float4 alignment)
#define PPAD4 (PPAD/4)

// ---------------------------------------------------------------------------
// Kernel W: repack fc_w [54][5625] -> [54][5632], zero-padded rows so each row
// is 16B-aligned for dwordx4 loads in the FC phase.
// ---------------------------------------------------------------------------
__global__ void repack_w(const float* __restrict__ fc_w, float* __restrict__ wpad) {
    int idx = blockIdx.x * blockDim.x + threadIdx.x;
    if (idx >= NEURONS * PPAD) return;
    int n = idx / PPAD, p = idx % PPAD;
    wpad[idx] = (p < P) ? fc_w[n * P + p] : 0.0f;
}

// ---------------------------------------------------------------------------
// Kernel F: fused 8x8 avg-pool + FC. One block per (b,t) frame.
//   Phase 1: pool 600x600 -> 75x75 into LDS (float4 loads, all 16B aligned:
//            rows are 2400B, block col starts are 32B multiples).
//   Phase 2: 432 threads (54 neurons x 8 chunks) dot LDS row with fc_w row
//            (L2-resident, ~1.2MB), reduce partials, add bias, emit frame.
// ---------------------------------------------------------------------------
__global__ __launch_bounds__(512) void pool_fc(
    const float* __restrict__ x, const float* __restrict__ wpad,
    const float* __restrict__ fc_b, float* __restrict__ frames) {
    __shared__ __align__(16) float xp_s[PPAD];
    __shared__ float partial[NEURONS * 8];
    const int bt = blockIdx.x;           // b*30 + t, 0..479
    const int tid = threadIdx.x;
    const float* img = x + (size_t)bt * (600 * 600);

    if (tid < PPAD - P) xp_s[P + tid] = 0.0f;   // zero the pad tail

    // ---- pooling: each thread handles pooled pixels tid, tid+512, ... ----
    for (int p = tid; p < P; p += 512) {
        int ph = p / HW, pw = p - ph * HW;
        const float* base = img + (ph * 8) * 600 + pw * 8;
        float acc = 0.0f;
        #pragma unroll
        for (int r = 0; r < 8; r++) {
            const float4* row = (const float4*)(base + r * 600);
            float4 a = row[0], b4 = row[1];
            acc += (a.x + b4.x) + (a.y + b4.y) + (a.z + b4.z) + (a.w + b4.w);
        }
        xp_s[p] = acc * (1.0f / 64.0f);
    }
    __syncthreads();

    // ---- FC: n = tid/8, chunk c = tid%8, stride 8 float4s ----
    if (tid < NEURONS * 8) {
        int n = tid >> 3, c = tid & 7;
        const float4* w4 = (const float4*)(wpad + n * PPAD);
        const float4* x4 = (const float4*)xp_s;
        float acc = 0.0f;
        for (int i = c; i < PPAD4; i += 8) {
            float4 a = x4[i], w = w4[i];
            acc += a.x * w.x + a.y * w.y + a.z * w.z + a.w * w.w;
        }
        partial[tid] = acc;
    }
    __syncthreads();
    if (tid < NEURONS) {
        float s = 0.0f;
        #pragma unroll
        for (int c = 0; c < 8; c++) s += partial[tid * 8 + c];
        frames[bt * NEURONS + tid] = s + fc_b[tid];
    }
}

// ---------------------------------------------------------------------------
// Kernel S: 30-step recurrent scan. One block, 1024 threads.
// wave = batch b (16 waves), lane = neuron n (lanes 54..63 idle with 0s).
// hist[4]/count live in registers; per-b lateral sum and the global
// rate-mean are shuffle butterflies (+ one 16-float LDS hop for cross-wave).
// ---------------------------------------------------------------------------
__global__ __launch_bounds__(1024) void scan_k(
    const float* __restrict__ frames, const float* __restrict__ l_weight,
    const float* __restrict__ h_weight, float* __restrict__ out) {
    const int tid = threadIdx.x;
    const int b = tid >> 6;     // wave id = batch
    const int n = tid & 63;     // lane = neuron
    const bool active = (n < NEURONS);

    float lw[DT], hw_[DT];
    #pragma unroll
    for (int d = 0; d < DT; d++) {
        lw[d]  = active ? l_weight[n * DT + d] : 0.0f;
        hw_[d] = h_weight[d];
    }
    float hist[DT] = {0.f, 0.f, 0.f, 0.f};
    float count = 0.f;
    __shared__ float wls[16];

    for (int t = 0; t < STEPS; t++) {
        float my_hsum = 0.f, hterm = 0.f;
        #pragma unroll
        for (int d = 0; d < DT; d++) {
            my_hsum += hist[d] * lw[d];
            hterm   += hist[d] * hw_[d];
        }
        // per-batch total of hsum (sum over 54 neurons; idle lanes contribute 0)
        float tot = my_hsum;
        #pragma unroll
        for (int off = 32; off > 0; off >>= 1) tot += __shfl_xor(tot, off, 64);

        float rate = 0.f;
        if (active) {
            float cur = frames[(b * STEPS + t) * NEURONS + n] + (tot - my_hsum) + hterm;
            rate = expf(cur);
        }
        // global mean of rate over all 16*54 values
        float rsum = rate;
        #pragma unroll
        for (int off = 32; off > 0; off >>= 1) rsum += __shfl_xor(rsum, off, 64);
        __syncthreads();                 // protect wls from previous iteration
        if (n == 0) wls[b] = rsum;
        __syncthreads();
        float v = (n < 16) ? wls[n] : 0.f;
        #pragma unroll
        for (int off = 32; off > 0; off >>= 1) v += __shfl_xor(v, off, 64);
        float thr = v * (1.0f / (BATCH * NEURONS));

        float s = (active && rate > thr) ? 1.0f : 0.0f;
        count += s;
        hist[0] = hist[1]; hist[1] = hist[2]; hist[2] = hist[3]; hist[3] = s;
    }
    if (active) {
        // softplus(count), count >= 0: count + log1p(exp(-count))
        out[b * NEURONS + n] = count + log1pf(expf(-count));
    }
}

extern "C" void kernel_launch(void* const* d_in, const int* in_sizes, int n_in,
                              void* d_out, int out_size, void* d_ws, size_t ws_size,
                              hipStream_t stream) {
    const float* x        = (const float*)d_in[0];
    const float* fc_w     = (const float*)d_in[1];
    const float* fc_b     = (const float*)d_in[2];
    const float* l_weight = (const float*)d_in[3];
    const float* h_weight = (const float*)d_in[4];
    float* out = (float*)d_out;

    float* wpad   = (float*)d_ws;                 // 54*5632 floats = 1.22 MB
    float* frames = wpad + NEURONS * PPAD;        // 480*54 floats  = 104 KB

    int wtotal = NEURONS * PPAD;
    repack_w<<<(wtotal + 511) / 512, 512, 0, stream>>>(fc_w, wpad);
    pool_fc<<<BATCH * STEPS, 512, 0, stream>>>(x, wpad, fc_b, frames);
    scan_k<<<1, 1024, 0, stream>>>(frames, l_weight, h_weight, out);
}